// Round 8
// baseline (467.906 us; speedup 1.0000x reference)
//
#include <hip/hip_runtime.h>
#include <hip/hip_bf16.h>
#include <hip/hip_cooperative_groups.h>
#include <math.h>

namespace cg = cooperative_groups;

#define B_ 2
#define N_ 6
#define C_ 80
#define FH_ 16
#define FW_ 44
#define HW_ (FH_ * FW_)             /* 704 */
#define D_ 112
#define NX_ 128
#define NY_ 128
#define NCOL (B_ * N_ * HW_)        /* 8448 */
#define NCELL (B_ * NY_ * NX_)      /* 32768 */
#define MAXT (NCOL * D_)            /* 946176 */
#define NBLK 256
#define NTHR 1024
#define NWAVES (NBLK * (NTHR / 64)) /* 4096 */

typedef __hip_bfloat16 bf16;
typedef unsigned short u16;

__device__ __forceinline__ float loadf(const void* p, int i, int isbf) {
  if (isbf) return __bfloat162float(((const bf16*)p)[i]);
  return ((const float*)p)[i];
}

__device__ __forceinline__ int probe_tbf(const void* logits) {
  int lane = threadIdx.x & 63;
  unsigned short v = ((const unsigned short*)logits)[2 * lane];
  int e = (v >> 7) & 0xFF;
  int ok = (v == 0) || (e >= 110 && e <= 136);
  return __popcll(__ballot(ok)) > 42;
}
__device__ __forceinline__ int probe_mbf(const void* intrin) {
  float v = ((const float*)intrin)[0];
  return !(v > 100.f && v < 1.0e6f);
}

__device__ __forceinline__ void inv4(const float m[16], float invOut[16]) {
  float inv[16];
  inv[0]  =  m[5]*m[10]*m[15] - m[5]*m[11]*m[14] - m[9]*m[6]*m[15] + m[9]*m[7]*m[14] + m[13]*m[6]*m[11] - m[13]*m[7]*m[10];
  inv[4]  = -m[4]*m[10]*m[15] + m[4]*m[11]*m[14] + m[8]*m[6]*m[15] - m[8]*m[7]*m[14] - m[12]*m[6]*m[11] + m[12]*m[7]*m[10];
  inv[8]  =  m[4]*m[9]*m[15]  - m[4]*m[11]*m[13] - m[8]*m[5]*m[15] + m[8]*m[7]*m[13] + m[12]*m[5]*m[11] - m[12]*m[7]*m[9];
  inv[12] = -m[4]*m[9]*m[14]  + m[4]*m[10]*m[13] + m[8]*m[5]*m[14] - m[8]*m[6]*m[13] - m[12]*m[5]*m[10] + m[12]*m[6]*m[9];
  inv[1]  = -m[1]*m[10]*m[15] + m[1]*m[11]*m[14] + m[9]*m[2]*m[15] - m[9]*m[3]*m[14] - m[13]*m[2]*m[11] + m[13]*m[3]*m[10];
  inv[5]  =  m[0]*m[10]*m[15] - m[0]*m[11]*m[14] - m[8]*m[2]*m[15] + m[8]*m[3]*m[14] + m[12]*m[2]*m[11] - m[12]*m[3]*m[10];
  inv[9]  = -m[0]*m[9]*m[15]  + m[0]*m[11]*m[13] + m[8]*m[1]*m[15] - m[8]*m[3]*m[13] - m[12]*m[1]*m[11] + m[12]*m[3]*m[9];
  inv[13] =  m[0]*m[9]*m[14]  - m[0]*m[10]*m[13] - m[8]*m[1]*m[14] + m[8]*m[2]*m[13] + m[12]*m[1]*m[10] - m[12]*m[2]*m[9];
  inv[2]  =  m[1]*m[6]*m[15]  - m[1]*m[7]*m[14]  - m[5]*m[2]*m[15] + m[5]*m[3]*m[14] + m[13]*m[2]*m[7]  - m[13]*m[3]*m[6];
  inv[6]  = -m[0]*m[6]*m[15]  + m[0]*m[7]*m[14]  + m[4]*m[2]*m[15] - m[4]*m[3]*m[14] - m[12]*m[2]*m[7]  + m[12]*m[3]*m[6];
  inv[10] =  m[0]*m[5]*m[15]  - m[0]*m[7]*m[13]  - m[4]*m[1]*m[15] + m[4]*m[3]*m[13] + m[12]*m[1]*m[7]  - m[12]*m[3]*m[5];
  inv[14] = -m[0]*m[5]*m[14]  + m[0]*m[6]*m[13]  + m[4]*m[1]*m[14] - m[4]*m[2]*m[13] - m[12]*m[1]*m[6]  + m[12]*m[2]*m[5];
  inv[3]  = -m[1]*m[6]*m[11]  + m[1]*m[7]*m[10]  + m[5]*m[2]*m[11] - m[5]*m[3]*m[10] - m[9]*m[2]*m[7]   + m[9]*m[3]*m[6];
  inv[7]  =  m[0]*m[6]*m[11]  - m[0]*m[7]*m[10]  - m[4]*m[2]*m[11] + m[4]*m[3]*m[10] + m[8]*m[2]*m[7]   - m[8]*m[3]*m[6];
  inv[11] = -m[0]*m[5]*m[11]  + m[0]*m[7]*m[9]   + m[4]*m[1]*m[11] - m[4]*m[3]*m[9]  - m[8]*m[1]*m[7]   + m[8]*m[3]*m[5];
  inv[15] =  m[0]*m[5]*m[10]  - m[0]*m[6]*m[9]   - m[4]*m[1]*m[10] + m[4]*m[2]*m[9]  + m[8]*m[1]*m[6]   - m[8]*m[2]*m[5];
  float det = m[0]*inv[0] + m[1]*inv[4] + m[2]*inv[8] + m[3]*inv[12];
  det = 1.0f / det;
  for (int i = 0; i < 16; i++) invOut[i] = inv[i] * det;
}

__device__ __forceinline__ void mul4(const float A[16], const float Bm[16], float Cm[16]) {
  for (int i = 0; i < 4; i++)
    for (int j = 0; j < 4; j++) {
      float s = 0.f;
      for (int k = 0; k < 4; k++) s += A[i * 4 + k] * Bm[k * 4 + j];
      Cm[i * 4 + j] = s;
    }
}

__device__ __forceinline__ void fold_mats(const void* s2e, const void* intrin,
                                          const void* ida, const void* bda, int bn,
                                          float Ainv[16], float M[16]) {
  const int mbf = probe_mbf(intrin);
  const int b = bn / N_;
  float S[16], I[16], A[16], Bd[16], Iinv[16], Cm[16];
  for (int i = 0; i < 16; i++) {
    S[i]  = loadf(s2e,    bn * 16 + i, mbf);
    I[i]  = loadf(intrin, bn * 16 + i, mbf);
    A[i]  = loadf(ida,    bn * 16 + i, mbf);
    Bd[i] = loadf(bda,    b * 16 + i, mbf);
  }
  inv4(I, Iinv);
  inv4(A, Ainv);
  mul4(S, Iinv, Cm);
  mul4(Bd, Cm, M);
}

__device__ __forceinline__ int geom_cell(const float Ai[16], const float M[16],
                                         int bn, int h, int w, int d) {
  float u = (float)w * (703.0f / 43.0f);
  float v = (float)h * 17.0f;
  float dep = 2.25f + 0.5f * (float)d;
  float p0 = ((Ai[0] * u + Ai[1] * v) + Ai[2] * dep) + Ai[3];
  float p1 = ((Ai[4] * u + Ai[5] * v) + Ai[6] * dep) + Ai[7];
  float p2 = ((Ai[8] * u + Ai[9] * v) + Ai[10] * dep) + Ai[11];
  float p3 = ((Ai[12] * u + Ai[13] * v) + Ai[14] * dep) + Ai[15];
  float q0 = p0 * p2, q1 = p1 * p2;
  float gx = ((M[0] * q0 + M[1] * q1) + M[2] * p2) + M[3] * p3;
  float gy = ((M[4] * q0 + M[5] * q1) + M[6] * p2) + M[7] * p3;
  float gz = ((M[8] * q0 + M[9] * q1) + M[10] * p2) + M[11] * p3;
  int ix = (int)floorf((gx + 51.2f) / 0.8f);
  int iy = (int)floorf((gy + 51.2f) / 0.8f);
  int iz = (int)floorf((gz + 5.0f) / 8.0f);
  bool valid = (ix >= 0) && (ix < NX_) && (iy >= 0) && (iy < NY_) && (iz == 0);
  int b = bn / N_;
  return valid ? (b * (NY_ * NX_) + iy * NX_ + ix) : -1;
}

__global__ __launch_bounds__(NTHR, 4) void lss_mega(
    const void* __restrict__ ctx, const void* __restrict__ logits,
    const void* __restrict__ s2e, const void* __restrict__ intrin,
    const void* __restrict__ ida, const void* __restrict__ bda,
    float* __restrict__ ctx_t, float* __restrict__ logits_t,
    int* __restrict__ counts, int* __restrict__ offsets,
    int* __restrict__ cursors, int* __restrict__ gsums,
    u16* __restrict__ colids, float* __restrict__ wts,
    void* __restrict__ out) {
  cg::grid_group grid = cg::this_grid();
  __shared__ union {
    float tile[16][65];                              // phase A
    struct { int cell[16][D_]; float w[16][D_]; } cf; // phases B, D
    int tmp[256];                                     // phase C
    float stage[64 * 81];                             // phase E
  } sm;
  const int tid = threadIdx.x;
  const int bid = blockIdx.x;
  const int lane = tid & 63;
  const int widx = tid >> 6;
  const int wgid = bid * (NTHR / 64) + widx;
  const int tbf = probe_tbf(logits);

  // ================= Phase A: LDS-tiled transposes, both sides coalesced ====
  const int CT = B_ * N_ * (C_ / 16) * (HW_ / 64);   // 660 ctx tiles
  const int LT = B_ * N_ * (D_ / 16) * (HW_ / 64);   // 924 logits tiles
  {
    const int ty = tid >> 6, tx = tid & 63;          // load layout 16x64
    const int tx2 = tid & 15, ty2 = tid >> 4;        // store layout 64x16
    for (int t = bid; t < CT + LT; t += NBLK) {
      if (t < CT) {
        int bn = t / 55, rem = t % 55;
        int c0 = (rem / 11) * 16, hw0 = (rem % 11) * 64;
        sm.tile[ty][tx] = loadf(ctx, (bn * C_ + c0 + ty) * HW_ + hw0 + tx, tbf);
        __syncthreads();
        ctx_t[(bn * HW_ + hw0 + ty2) * C_ + c0 + tx2] = sm.tile[tx2][ty2];
      } else {
        int t2 = t - CT;
        int bn = t2 / 77, rem = t2 % 77;
        int d0 = (rem / 11) * 16, hw0 = (rem % 11) * 64;
        sm.tile[ty][tx] = loadf(logits, (bn * D_ + d0 + ty) * HW_ + hw0 + tx, tbf);
        __syncthreads();
        logits_t[(bn * HW_ + hw0 + ty2) * D_ + d0 + tx2] = sm.tile[tx2][ty2];
      }
      __syncthreads();
    }
  }

  // ================= Phase B: per-column geometry count (counts pre-zeroed) =
  for (int i = 0; i < 3; i++) {
    int col = wgid + i * NWAVES;
    int active = col < NCOL;
    if (active) {
      int w = col % FW_, h = (col / FW_) % FH_, bn = col / HW_;
      float Ai[16], M[16];
      fold_mats(s2e, intrin, ida, bda, bn, Ai, M);
      sm.cf.cell[widx][lane] = geom_cell(Ai, M, bn, h, w, lane);
      if (lane < D_ - 64)
        sm.cf.cell[widx][lane + 64] = geom_cell(Ai, M, bn, h, w, lane + 64);
    }
    __syncthreads();
    if (active) {
      for (int d = lane; d < D_; d += 64) {
        int vc = sm.cf.cell[widx][d];
        if (vc >= 0 && (d == 0 || sm.cf.cell[widx][d - 1] != vc))
          atomicAdd(&counts[vc], 1);
      }
    }
    __syncthreads();
  }
  grid.sync();

  // ================= Phase C: distributed exclusive scan =====================
  int myExcl = 0;
  {
    int myVal = 0;
    if (tid < 128) { myVal = counts[bid * 128 + tid]; sm.tmp[tid] = myVal; }
    __syncthreads();
    for (int st = 1; st < 128; st <<= 1) {
      int v = 0;
      if (tid < 128 && tid >= st) v = sm.tmp[tid - st];
      __syncthreads();
      if (tid < 128) sm.tmp[tid] += v;
      __syncthreads();
    }
    if (tid < 128) myExcl = sm.tmp[tid] - myVal;
    if (tid == 127) gsums[bid] = sm.tmp[127];
  }
  grid.sync();
  {
    // every block redundantly reduces gsums[j<bid] -> its global prefix
    if (tid < 256) sm.tmp[tid] = (tid < bid) ? gsums[tid] : 0;
    __syncthreads();
    for (int st = 128; st > 0; st >>= 1) {
      if (tid < st) sm.tmp[tid] += sm.tmp[tid + st];
      __syncthreads();
    }
    int gpref = sm.tmp[0];
    if (tid < 128) {
      int v = gpref + myExcl;
      offsets[bid * 128 + tid] = v;
      cursors[bid * 128 + tid] = v;
    }
    __syncthreads();
  }
  grid.sync();

  // ================= Phase D: softmax + tuple append ========================
  for (int i = 0; i < 3; i++) {
    int col = wgid + i * NWAVES;
    int active = col < NCOL;
    float inv_sum = 0.f;
    if (active) {
      int w = col % FW_, h = (col / FW_) % FH_, bn = col / HW_;
      float Ai[16], M[16];
      fold_mats(s2e, intrin, ida, bda, bn, Ai, M);
      float l0 = logits_t[col * D_ + lane];
      float l1 = (lane < D_ - 64) ? logits_t[col * D_ + 64 + lane] : -1e30f;
      float m = fmaxf(l0, l1);
      for (int s = 32; s > 0; s >>= 1) m = fmaxf(m, __shfl_xor(m, s));
      float e0 = expf(l0 - m);
      float e1 = (lane < D_ - 64) ? expf(l1 - m) : 0.f;
      float sum = e0 + e1;
      for (int s = 32; s > 0; s >>= 1) sum += __shfl_xor(sum, s);
      inv_sum = 1.0f / sum;
      sm.cf.cell[widx][lane] = geom_cell(Ai, M, bn, h, w, lane);
      sm.cf.w[widx][lane] = e0;
      if (lane < D_ - 64) {
        sm.cf.cell[widx][lane + 64] = geom_cell(Ai, M, bn, h, w, lane + 64);
        sm.cf.w[widx][lane + 64] = e1;
      }
    }
    __syncthreads();
    if (active) {
      for (int d = lane; d < D_; d += 64) {
        int vc = sm.cf.cell[widx][d];
        if (vc >= 0 && (d == 0 || sm.cf.cell[widx][d - 1] != vc)) {
          float acc = sm.cf.w[widx][d];
          for (int j = d + 1; j < D_ && sm.cf.cell[widx][j] == vc; ++j)
            acc += sm.cf.w[widx][j];
          int pos = atomicAdd(&cursors[vc], 1);
          colids[pos] = (u16)col;
          wts[pos] = acc * inv_sum;
        }
      }
    }
    __syncthreads();
  }
  grid.sync();

  // ================= Phase E: gather (4 cells/wave, 4 slices x 4 ch-groups) =
  for (int p = 0; p < 2; p++) {
    int cb = bid + p * NBLK;              // 512 cell-blocks of 64 cells
    int cell0 = cb * 64;
    int cl = widx * 4 + (lane >> 4);      // local cell 0..63
    int sl = (lane >> 2) & 3;             // j-slice
    int g = lane & 3;                     // channel quarter (20 ch)
    int cell = cell0 + cl;
    int n = counts[cell];
    int off = offsets[cell];
    float acc[20];
#pragma unroll
    for (int i = 0; i < 20; i++) acc[i] = 0.f;
    for (int j = sl; j < n; j += 4) {
      int colj = colids[off + j];
      float wj = wts[off + j];
      const float4* cp = (const float4*)(ctx_t + colj * C_ + g * 20);
#pragma unroll
      for (int q = 0; q < 5; q++) {
        float4 v = cp[q];
        acc[q * 4 + 0] += wj * v.x;
        acc[q * 4 + 1] += wj * v.y;
        acc[q * 4 + 2] += wj * v.z;
        acc[q * 4 + 3] += wj * v.w;
      }
    }
#pragma unroll
    for (int msk = 4; msk <= 8; msk <<= 1) {
#pragma unroll
      for (int i = 0; i < 20; i++) acc[i] += __shfl_xor(acc[i], msk);
    }
    if (sl == 0) {
#pragma unroll
      for (int i = 0; i < 20; i++) sm.stage[cl * 81 + g * 20 + i] = acc[i];
    }
    __syncthreads();
    {
      int b = cell0 >> 14;
      int yx0 = cell0 & 16383;
      int x = tid & 63;
#pragma unroll
      for (int it = 0; it < 5; it++) {
        int c = (tid >> 6) + it * 16;
        float val = sm.stage[x * 81 + c];
        size_t oi = ((size_t)(b * C_ + c) << 14) + yx0 + x;
        if (tbf) ((bf16*)out)[oi] = __float2bfloat16(val);
        else ((float*)out)[oi] = val;
      }
    }
    __syncthreads();
  }
}

extern "C" void kernel_launch(void* const* d_in, const int* in_sizes, int n_in,
                              void* d_out, int out_size, void* d_ws, size_t ws_size,
                              hipStream_t stream) {
  const void* ctx = d_in[0];
  const void* logits = d_in[1];
  const void* s2e = d_in[2];
  const void* intrin = d_in[3];
  const void* ida = d_in[4];
  const void* bda = d_in[5];

  int* counts     = (int*)d_ws;
  int* offsets    = counts + NCELL;
  int* cursors    = offsets + NCELL;
  int* gsums      = cursors + NCELL;
  float* ctx_t    = (float*)(gsums + 256);
  float* logits_t = ctx_t + NCOL * C_;
  u16* colids     = (u16*)(logits_t + NCOL * D_);
  float* wts      = (float*)(colids + MAXT);
  void* outp      = d_out;

  hipMemsetAsync(counts, 0, NCELL * sizeof(int), stream);
  void* args[] = {(void*)&ctx, (void*)&logits, (void*)&s2e, (void*)&intrin,
                  (void*)&ida, (void*)&bda, (void*)&ctx_t, (void*)&logits_t,
                  (void*)&counts, (void*)&offsets, (void*)&cursors, (void*)&gsums,
                  (void*)&colids, (void*)&wts, (void*)&outp};
  hipLaunchCooperativeKernel((void*)lss_mega, dim3(NBLK), dim3(NTHR), args, 0, stream);
}

// Round 9
// 309.328 us; speedup vs baseline: 1.5127x; 1.5127x over previous
//
#include <hip/hip_runtime.h>
#include <hip/hip_bf16.h>
#include <hip/hip_cooperative_groups.h>
#include <math.h>

namespace cg = cooperative_groups;

#define B_ 2
#define N_ 6
#define C_ 80
#define FH_ 16
#define FW_ 44
#define HW_ (FH_ * FW_)             /* 704 */
#define D_ 112
#define NX_ 128
#define NY_ 128
#define NCOL (B_ * N_ * HW_)        /* 8448 */
#define NCELL (B_ * NY_ * NX_)      /* 32768 */
#define MAXT (NCOL * D_)            /* 946176 */
#define NBLK 256
#define NTHR 1024
#define NWAVES (NBLK * (NTHR / 64)) /* 4096 */

typedef __hip_bfloat16 bf16;
typedef unsigned short u16;

__device__ __forceinline__ float loadf(const void* p, int i, int isbf) {
  if (isbf) return __bfloat162float(((const bf16*)p)[i]);
  return ((const float*)p)[i];
}

__device__ __forceinline__ int probe_tbf(const void* logits) {
  int lane = threadIdx.x & 63;
  unsigned short v = ((const unsigned short*)logits)[2 * lane];
  int e = (v >> 7) & 0xFF;
  int ok = (v == 0) || (e >= 110 && e <= 136);
  return __popcll(__ballot(ok)) > 42;
}
__device__ __forceinline__ int probe_mbf(const void* intrin) {
  float v = ((const float*)intrin)[0];
  return !(v > 100.f && v < 1.0e6f);
}

__device__ __forceinline__ void inv4(const float m[16], float invOut[16]) {
  float inv[16];
  inv[0]  =  m[5]*m[10]*m[15] - m[5]*m[11]*m[14] - m[9]*m[6]*m[15] + m[9]*m[7]*m[14] + m[13]*m[6]*m[11] - m[13]*m[7]*m[10];
  inv[4]  = -m[4]*m[10]*m[15] + m[4]*m[11]*m[14] + m[8]*m[6]*m[15] - m[8]*m[7]*m[14] - m[12]*m[6]*m[11] + m[12]*m[7]*m[10];
  inv[8]  =  m[4]*m[9]*m[15]  - m[4]*m[11]*m[13] - m[8]*m[5]*m[15] + m[8]*m[7]*m[13] + m[12]*m[5]*m[11] - m[12]*m[7]*m[9];
  inv[12] = -m[4]*m[9]*m[14]  + m[4]*m[10]*m[13] + m[8]*m[5]*m[14] - m[8]*m[6]*m[13] - m[12]*m[5]*m[10] + m[12]*m[6]*m[9];
  inv[1]  = -m[1]*m[10]*m[15] + m[1]*m[11]*m[14] + m[9]*m[2]*m[15] - m[9]*m[3]*m[14] - m[13]*m[2]*m[11] + m[13]*m[3]*m[10];
  inv[5]  =  m[0]*m[10]*m[15] - m[0]*m[11]*m[14] - m[8]*m[2]*m[15] + m[8]*m[3]*m[14] + m[12]*m[2]*m[11] - m[12]*m[3]*m[10];
  inv[9]  = -m[0]*m[9]*m[15]  + m[0]*m[11]*m[13] + m[8]*m[1]*m[15] - m[8]*m[3]*m[13] - m[12]*m[1]*m[11] + m[12]*m[3]*m[9];
  inv[13] =  m[0]*m[9]*m[14]  - m[0]*m[10]*m[13] - m[8]*m[1]*m[14] + m[8]*m[2]*m[13] + m[12]*m[1]*m[10] - m[12]*m[2]*m[9];
  inv[2]  =  m[1]*m[6]*m[15]  - m[1]*m[7]*m[14]  - m[5]*m[2]*m[15] + m[5]*m[3]*m[14] + m[13]*m[2]*m[7]  - m[13]*m[3]*m[6];
  inv[6]  = -m[0]*m[6]*m[15]  + m[0]*m[7]*m[14]  + m[4]*m[2]*m[15] - m[4]*m[3]*m[14] - m[12]*m[2]*m[7]  + m[12]*m[3]*m[6];
  inv[10] =  m[0]*m[5]*m[15]  - m[0]*m[7]*m[13]  - m[4]*m[1]*m[15] + m[4]*m[3]*m[13] + m[12]*m[1]*m[7]  - m[12]*m[3]*m[5];
  inv[14] = -m[0]*m[5]*m[14]  + m[0]*m[6]*m[13]  + m[4]*m[1]*m[14] - m[4]*m[2]*m[13] - m[12]*m[1]*m[6]  + m[12]*m[2]*m[5];
  inv[3]  = -m[1]*m[6]*m[11]  + m[1]*m[7]*m[10]  + m[5]*m[2]*m[11] - m[5]*m[3]*m[10] - m[9]*m[2]*m[7]   + m[9]*m[3]*m[6];
  inv[7]  =  m[0]*m[6]*m[11]  - m[0]*m[7]*m[10]  - m[4]*m[2]*m[11] + m[4]*m[3]*m[10] + m[8]*m[2]*m[7]   - m[8]*m[3]*m[6];
  inv[11] = -m[0]*m[5]*m[11]  + m[0]*m[7]*m[9]   + m[4]*m[1]*m[11] - m[4]*m[3]*m[9]  - m[8]*m[1]*m[7]   + m[8]*m[3]*m[5];
  inv[15] =  m[0]*m[5]*m[10]  - m[0]*m[6]*m[9]   - m[4]*m[1]*m[10] + m[4]*m[2]*m[9]  + m[8]*m[1]*m[6]   - m[8]*m[2]*m[5];
  float det = m[0]*inv[0] + m[1]*inv[4] + m[2]*inv[8] + m[3]*inv[12];
  det = 1.0f / det;
  for (int i = 0; i < 16; i++) invOut[i] = inv[i] * det;
}

__device__ __forceinline__ void mul4(const float A[16], const float Bm[16], float Cm[16]) {
  for (int i = 0; i < 4; i++)
    for (int j = 0; j < 4; j++) {
      float s = 0.f;
      for (int k = 0; k < 4; k++) s += A[i * 4 + k] * Bm[k * 4 + j];
      Cm[i * 4 + j] = s;
    }
}

// geometry with mats in LDS (wave-uniform broadcast reads, static offsets)
__device__ __forceinline__ int geom_cell(const float* __restrict__ Ai,
                                         const float* __restrict__ M,
                                         int bn, int h, int w, int d) {
  float u = (float)w * (703.0f / 43.0f);
  float v = (float)h * 17.0f;
  float dep = 2.25f + 0.5f * (float)d;
  float p0 = ((Ai[0] * u + Ai[1] * v) + Ai[2] * dep) + Ai[3];
  float p1 = ((Ai[4] * u + Ai[5] * v) + Ai[6] * dep) + Ai[7];
  float p2 = ((Ai[8] * u + Ai[9] * v) + Ai[10] * dep) + Ai[11];
  float p3 = ((Ai[12] * u + Ai[13] * v) + Ai[14] * dep) + Ai[15];
  float q0 = p0 * p2, q1 = p1 * p2;
  float gx = ((M[0] * q0 + M[1] * q1) + M[2] * p2) + M[3] * p3;
  float gy = ((M[4] * q0 + M[5] * q1) + M[6] * p2) + M[7] * p3;
  float gz = ((M[8] * q0 + M[9] * q1) + M[10] * p2) + M[11] * p3;
  int ix = (int)floorf((gx + 51.2f) / 0.8f);
  int iy = (int)floorf((gy + 51.2f) / 0.8f);
  int iz = (int)floorf((gz + 5.0f) / 8.0f);
  bool valid = (ix >= 0) && (ix < NX_) && (iy >= 0) && (iy < NY_) && (iz == 0);
  int b = bn / N_;
  return valid ? (b * (NY_ * NX_) + iy * NX_ + ix) : -1;
}

__global__ __launch_bounds__(NTHR) void lss_mega(
    const void* __restrict__ ctx, const void* __restrict__ logits,
    const void* __restrict__ s2e, const void* __restrict__ intrin,
    const void* __restrict__ ida, const void* __restrict__ bda,
    float* __restrict__ ctx_t, float* __restrict__ logits_t,
    int* __restrict__ counts, int* __restrict__ offsets,
    int* __restrict__ cursors, int* __restrict__ gsums,
    u16* __restrict__ colids, float* __restrict__ wts,
    void* __restrict__ out) {
  cg::grid_group grid = cg::this_grid();
  __shared__ union {
    float tile[16][65];                               // phase A
    struct { int cell[16][D_]; float w[16][D_]; } cf; // phases B, D
    int tmp[256];                                     // phase C
    float stage[64 * 81];                             // phase E
  } sm;
  __shared__ float s_mats[B_ * N_][32];               // [bn]: Ainv[0:16], M[16:32]
  const int tid = threadIdx.x;
  const int bid = blockIdx.x;
  const int lane = tid & 63;
  const int widx = tid >> 6;
  const int wgid = bid * (NTHR / 64) + widx;
  const int tbf = probe_tbf(logits);

  // ===== Phase 0: per-block matrix fold, ONCE (tid 0..11), sequential low-
  // pressure structure (peak ~70 live floats; executed 256x total, not 24K) ==
  if (tid < B_ * N_) {
    const int bn = tid, b = bn / N_;
    const int mbf = probe_mbf(intrin);
    float T[16], U[16], R[16];
    for (int i = 0; i < 16; i++) T[i] = loadf(intrin, bn * 16 + i, mbf);
    inv4(T, R);                                   // R = inv(intrin)
    for (int i = 0; i < 16; i++) T[i] = loadf(s2e, bn * 16 + i, mbf);
    mul4(T, R, U);                                // U = s2e * inv(intrin)
    for (int i = 0; i < 16; i++) T[i] = loadf(bda, b * 16 + i, mbf);
    mul4(T, U, R);                                // R = bda * U
    for (int i = 0; i < 16; i++) s_mats[bn][16 + i] = R[i];
    for (int i = 0; i < 16; i++) T[i] = loadf(ida, bn * 16 + i, mbf);
    inv4(T, U);                                   // U = inv(ida)
    for (int i = 0; i < 16; i++) s_mats[bn][i] = U[i];
  }
  __syncthreads();

  // ================= Phase A: LDS-tiled transposes, both sides coalesced ====
  const int CT = B_ * N_ * (C_ / 16) * (HW_ / 64);   // 660 ctx tiles
  const int LT = B_ * N_ * (D_ / 16) * (HW_ / 64);   // 924 logits tiles
  {
    const int ty = tid >> 6, tx = tid & 63;          // load layout 16x64
    const int tx2 = tid & 15, ty2 = tid >> 4;        // store layout 64x16
    for (int t = bid; t < CT + LT; t += NBLK) {
      if (t < CT) {
        int bn = t / 55, rem = t % 55;
        int c0 = (rem / 11) * 16, hw0 = (rem % 11) * 64;
        sm.tile[ty][tx] = loadf(ctx, (bn * C_ + c0 + ty) * HW_ + hw0 + tx, tbf);
        __syncthreads();
        ctx_t[(bn * HW_ + hw0 + ty2) * C_ + c0 + tx2] = sm.tile[tx2][ty2];
      } else {
        int t2 = t - CT;
        int bn = t2 / 77, rem = t2 % 77;
        int d0 = (rem / 11) * 16, hw0 = (rem % 11) * 64;
        sm.tile[ty][tx] = loadf(logits, (bn * D_ + d0 + ty) * HW_ + hw0 + tx, tbf);
        __syncthreads();
        logits_t[(bn * HW_ + hw0 + ty2) * D_ + d0 + tx2] = sm.tile[tx2][ty2];
      }
      __syncthreads();
    }
  }

  // ================= Phase B: per-column geometry count (counts pre-zeroed) =
  for (int i = 0; i < 3; i++) {
    int col = wgid + i * NWAVES;
    int active = col < NCOL;
    if (active) {
      int w = col % FW_, h = (col / FW_) % FH_, bn = col / HW_;
      const float* Ai = s_mats[bn];
      const float* M = s_mats[bn] + 16;
      sm.cf.cell[widx][lane] = geom_cell(Ai, M, bn, h, w, lane);
      if (lane < D_ - 64)
        sm.cf.cell[widx][lane + 64] = geom_cell(Ai, M, bn, h, w, lane + 64);
    }
    __syncthreads();
    if (active) {
      for (int d = lane; d < D_; d += 64) {
        int vc = sm.cf.cell[widx][d];
        if (vc >= 0 && (d == 0 || sm.cf.cell[widx][d - 1] != vc))
          atomicAdd(&counts[vc], 1);
      }
    }
    __syncthreads();
  }
  grid.sync();

  // ================= Phase C: distributed exclusive scan ====================
  int myExcl = 0;
  {
    int myVal = 0;
    if (tid < 128) { myVal = counts[bid * 128 + tid]; sm.tmp[tid] = myVal; }
    __syncthreads();
    for (int st = 1; st < 128; st <<= 1) {
      int v = 0;
      if (tid < 128 && tid >= st) v = sm.tmp[tid - st];
      __syncthreads();
      if (tid < 128) sm.tmp[tid] += v;
      __syncthreads();
    }
    if (tid < 128) myExcl = sm.tmp[tid] - myVal;
    if (tid == 127) gsums[bid] = sm.tmp[127];
  }
  grid.sync();
  {
    if (tid < 256) sm.tmp[tid] = (tid < bid) ? gsums[tid] : 0;
    __syncthreads();
    for (int st = 128; st > 0; st >>= 1) {
      if (tid < st) sm.tmp[tid] += sm.tmp[tid + st];
      __syncthreads();
    }
    int gpref = sm.tmp[0];
    if (tid < 128) {
      int v = gpref + myExcl;
      offsets[bid * 128 + tid] = v;
      cursors[bid * 128 + tid] = v;
    }
    __syncthreads();
  }
  grid.sync();

  // ================= Phase D: softmax + tuple append ========================
  for (int i = 0; i < 3; i++) {
    int col = wgid + i * NWAVES;
    int active = col < NCOL;
    float inv_sum = 0.f;
    if (active) {
      int w = col % FW_, h = (col / FW_) % FH_, bn = col / HW_;
      const float* Ai = s_mats[bn];
      const float* M = s_mats[bn] + 16;
      float l0 = logits_t[col * D_ + lane];
      float l1 = (lane < D_ - 64) ? logits_t[col * D_ + 64 + lane] : -1e30f;
      float m = fmaxf(l0, l1);
      for (int s = 32; s > 0; s >>= 1) m = fmaxf(m, __shfl_xor(m, s));
      float e0 = expf(l0 - m);
      float e1 = (lane < D_ - 64) ? expf(l1 - m) : 0.f;
      float sum = e0 + e1;
      for (int s = 32; s > 0; s >>= 1) sum += __shfl_xor(sum, s);
      inv_sum = 1.0f / sum;
      sm.cf.cell[widx][lane] = geom_cell(Ai, M, bn, h, w, lane);
      sm.cf.w[widx][lane] = e0;
      if (lane < D_ - 64) {
        sm.cf.cell[widx][lane + 64] = geom_cell(Ai, M, bn, h, w, lane + 64);
        sm.cf.w[widx][lane + 64] = e1;
      }
    }
    __syncthreads();
    if (active) {
      for (int d = lane; d < D_; d += 64) {
        int vc = sm.cf.cell[widx][d];
        if (vc >= 0 && (d == 0 || sm.cf.cell[widx][d - 1] != vc)) {
          float acc = sm.cf.w[widx][d];
          for (int j = d + 1; j < D_ && sm.cf.cell[widx][j] == vc; ++j)
            acc += sm.cf.w[widx][j];
          int pos = atomicAdd(&cursors[vc], 1);
          colids[pos] = (u16)col;
          wts[pos] = acc * inv_sum;
        }
      }
    }
    __syncthreads();
  }
  grid.sync();

  // ================= Phase E: gather (4 cells/wave, 4 slices x 4 ch-groups) =
  for (int p = 0; p < 2; p++) {
    int cb = bid + p * NBLK;              // 512 cell-blocks of 64 cells
    int cell0 = cb * 64;
    int cl = widx * 4 + (lane >> 4);      // local cell 0..63
    int sl = (lane >> 2) & 3;             // j-slice
    int g = lane & 3;                     // channel quarter (20 ch)
    int cell = cell0 + cl;
    int n = counts[cell];
    int off = offsets[cell];
    float acc[20];
#pragma unroll
    for (int i = 0; i < 20; i++) acc[i] = 0.f;
    for (int j = sl; j < n; j += 4) {
      int colj = colids[off + j];
      float wj = wts[off + j];
      const float4* cp = (const float4*)(ctx_t + colj * C_ + g * 20);
#pragma unroll
      for (int q = 0; q < 5; q++) {
        float4 v = cp[q];
        acc[q * 4 + 0] += wj * v.x;
        acc[q * 4 + 1] += wj * v.y;
        acc[q * 4 + 2] += wj * v.z;
        acc[q * 4 + 3] += wj * v.w;
      }
    }
#pragma unroll
    for (int msk = 4; msk <= 8; msk <<= 1) {
#pragma unroll
      for (int i = 0; i < 20; i++) acc[i] += __shfl_xor(acc[i], msk);
    }
    if (sl == 0) {
#pragma unroll
      for (int i = 0; i < 20; i++) sm.stage[cl * 81 + g * 20 + i] = acc[i];
    }
    __syncthreads();
    {
      int b = cell0 >> 14;
      int yx0 = cell0 & 16383;
      int x = tid & 63;
#pragma unroll
      for (int it = 0; it < 5; it++) {
        int c = (tid >> 6) + it * 16;
        float val = sm.stage[x * 81 + c];
        size_t oi = ((size_t)(b * C_ + c) << 14) + yx0 + x;
        if (tbf) ((bf16*)out)[oi] = __float2bfloat16(val);
        else ((float*)out)[oi] = val;
      }
    }
    __syncthreads();
  }
}

extern "C" void kernel_launch(void* const* d_in, const int* in_sizes, int n_in,
                              void* d_out, int out_size, void* d_ws, size_t ws_size,
                              hipStream_t stream) {
  const void* ctx = d_in[0];
  const void* logits = d_in[1];
  const void* s2e = d_in[2];
  const void* intrin = d_in[3];
  const void* ida = d_in[4];
  const void* bda = d_in[5];

  int* counts     = (int*)d_ws;
  int* offsets    = counts + NCELL;
  int* cursors    = offsets + NCELL;
  int* gsums      = cursors + NCELL;
  float* ctx_t    = (float*)(gsums + 256);
  float* logits_t = ctx_t + NCOL * C_;
  u16* colids     = (u16*)(logits_t + NCOL * D_);
  float* wts      = (float*)(colids + MAXT);
  void* outp      = d_out;

  hipMemsetAsync(counts, 0, NCELL * sizeof(int), stream);
  void* args[] = {(void*)&ctx, (void*)&logits, (void*)&s2e, (void*)&intrin,
                  (void*)&ida, (void*)&bda, (void*)&ctx_t, (void*)&logits_t,
                  (void*)&counts, (void*)&offsets, (void*)&cursors, (void*)&gsums,
                  (void*)&colids, (void*)&wts, (void*)&outp};
  hipLaunchCooperativeKernel((void*)lss_mega, dim3(NBLK), dim3(NTHR), args, 0, stream);
}

// Round 10
// 279.051 us; speedup vs baseline: 1.6768x; 1.1085x over previous
//
#include <hip/hip_runtime.h>
#include <hip/hip_bf16.h>
#include <hip/hip_cooperative_groups.h>
#include <math.h>

namespace cg = cooperative_groups;

#define B_ 2
#define N_ 6
#define C_ 80
#define FH_ 16
#define FW_ 44
#define HW_ (FH_ * FW_)             /* 704 */
#define D_ 112
#define NX_ 128
#define NY_ 128
#define NCOL (B_ * N_ * HW_)        /* 8448 */
#define NCELL (B_ * NY_ * NX_)      /* 32768 */
#define MAXT (NCOL * D_)            /* 946176 */
#define NBLK 256
#define NTHR 1024
#define NWAVES (NBLK * (NTHR / 64)) /* 4096 */

typedef __hip_bfloat16 bf16;
typedef unsigned short u16;

__device__ __forceinline__ float loadf(const void* p, int i, int isbf) {
  if (isbf) return __bfloat162float(((const bf16*)p)[i]);
  return ((const float*)p)[i];
}

__device__ __forceinline__ int probe_tbf(const void* logits) {
  int lane = threadIdx.x & 63;
  unsigned short v = ((const unsigned short*)logits)[2 * lane];
  int e = (v >> 7) & 0xFF;
  int ok = (v == 0) || (e >= 110 && e <= 136);
  return __popcll(__ballot(ok)) > 42;
}
__device__ __forceinline__ int probe_mbf(const void* intrin) {
  float v = ((const float*)intrin)[0];
  return !(v > 100.f && v < 1.0e6f);
}

__device__ __forceinline__ void inv4(const float m[16], float invOut[16]) {
  float inv[16];
  inv[0]  =  m[5]*m[10]*m[15] - m[5]*m[11]*m[14] - m[9]*m[6]*m[15] + m[9]*m[7]*m[14] + m[13]*m[6]*m[11] - m[13]*m[7]*m[10];
  inv[4]  = -m[4]*m[10]*m[15] + m[4]*m[11]*m[14] + m[8]*m[6]*m[15] - m[8]*m[7]*m[14] - m[12]*m[6]*m[11] + m[12]*m[7]*m[10];
  inv[8]  =  m[4]*m[9]*m[15]  - m[4]*m[11]*m[13] - m[8]*m[5]*m[15] + m[8]*m[7]*m[13] + m[12]*m[5]*m[11] - m[12]*m[7]*m[9];
  inv[12] = -m[4]*m[9]*m[14]  + m[4]*m[10]*m[13] + m[8]*m[5]*m[14] - m[8]*m[6]*m[13] - m[12]*m[5]*m[10] + m[12]*m[6]*m[9];
  inv[1]  = -m[1]*m[10]*m[15] + m[1]*m[11]*m[14] + m[9]*m[2]*m[15] - m[9]*m[3]*m[14] - m[13]*m[2]*m[11] + m[13]*m[3]*m[10];
  inv[5]  =  m[0]*m[10]*m[15] - m[0]*m[11]*m[14] - m[8]*m[2]*m[15] + m[8]*m[3]*m[14] + m[12]*m[2]*m[11] - m[12]*m[3]*m[10];
  inv[9]  = -m[0]*m[9]*m[15]  + m[0]*m[11]*m[13] + m[8]*m[1]*m[15] - m[8]*m[3]*m[13] - m[12]*m[1]*m[11] + m[12]*m[3]*m[9];
  inv[13] =  m[0]*m[9]*m[14]  - m[0]*m[10]*m[13] - m[8]*m[1]*m[14] + m[8]*m[2]*m[13] + m[12]*m[1]*m[10] - m[12]*m[2]*m[9];
  inv[2]  =  m[1]*m[6]*m[15]  - m[1]*m[7]*m[14]  - m[5]*m[2]*m[15] + m[5]*m[3]*m[14] + m[13]*m[2]*m[7]  - m[13]*m[3]*m[6];
  inv[6]  = -m[0]*m[6]*m[15]  + m[0]*m[7]*m[14]  + m[4]*m[2]*m[15] - m[4]*m[3]*m[14] - m[12]*m[2]*m[7]  + m[12]*m[3]*m[6];
  inv[10] =  m[0]*m[5]*m[15]  - m[0]*m[7]*m[13]  - m[4]*m[1]*m[15] + m[4]*m[3]*m[13] + m[12]*m[1]*m[7]  - m[12]*m[3]*m[5];
  inv[14] = -m[0]*m[5]*m[14]  + m[0]*m[6]*m[13]  + m[4]*m[1]*m[14] - m[4]*m[2]*m[13] - m[12]*m[1]*m[6]  + m[12]*m[2]*m[5];
  inv[3]  = -m[1]*m[6]*m[11]  + m[1]*m[7]*m[10]  + m[5]*m[2]*m[11] - m[5]*m[3]*m[10] - m[9]*m[2]*m[7]   + m[9]*m[3]*m[6];
  inv[7]  =  m[0]*m[6]*m[11]  - m[0]*m[7]*m[10]  - m[4]*m[2]*m[11] + m[4]*m[3]*m[10] + m[8]*m[2]*m[7]   - m[8]*m[3]*m[6];
  inv[11] = -m[0]*m[5]*m[11]  + m[0]*m[7]*m[9]   + m[4]*m[1]*m[11] - m[4]*m[3]*m[9]  - m[8]*m[1]*m[7]   + m[8]*m[3]*m[5];
  inv[15] =  m[0]*m[5]*m[10]  - m[0]*m[6]*m[9]   - m[4]*m[1]*m[10] + m[4]*m[2]*m[9]  + m[8]*m[1]*m[6]   - m[8]*m[2]*m[5];
  float det = m[0]*inv[0] + m[1]*inv[4] + m[2]*inv[8] + m[3]*inv[12];
  det = 1.0f / det;
  for (int i = 0; i < 16; i++) invOut[i] = inv[i] * det;
}

__device__ __forceinline__ void mul4(const float A[16], const float Bm[16], float Cm[16]) {
  for (int i = 0; i < 4; i++)
    for (int j = 0; j < 4; j++) {
      float s = 0.f;
      for (int k = 0; k < 4; k++) s += A[i * 4 + k] * Bm[k * 4 + j];
      Cm[i * 4 + j] = s;
    }
}

__device__ __forceinline__ int geom_cell(const float* __restrict__ Ai,
                                         const float* __restrict__ M,
                                         int bn, int h, int w, int d) {
  float u = (float)w * (703.0f / 43.0f);
  float v = (float)h * 17.0f;
  float dep = 2.25f + 0.5f * (float)d;
  float p0 = ((Ai[0] * u + Ai[1] * v) + Ai[2] * dep) + Ai[3];
  float p1 = ((Ai[4] * u + Ai[5] * v) + Ai[6] * dep) + Ai[7];
  float p2 = ((Ai[8] * u + Ai[9] * v) + Ai[10] * dep) + Ai[11];
  float p3 = ((Ai[12] * u + Ai[13] * v) + Ai[14] * dep) + Ai[15];
  float q0 = p0 * p2, q1 = p1 * p2;
  float gx = ((M[0] * q0 + M[1] * q1) + M[2] * p2) + M[3] * p3;
  float gy = ((M[4] * q0 + M[5] * q1) + M[6] * p2) + M[7] * p3;
  float gz = ((M[8] * q0 + M[9] * q1) + M[10] * p2) + M[11] * p3;
  int ix = (int)floorf((gx + 51.2f) / 0.8f);
  int iy = (int)floorf((gy + 51.2f) / 0.8f);
  int iz = (int)floorf((gz + 5.0f) / 8.0f);
  bool valid = (ix >= 0) && (ix < NX_) && (iy >= 0) && (iy < NY_) && (iz == 0);
  int b = bn / N_;
  return valid ? (b * (NY_ * NX_) + iy * NX_ + ix) : -1;
}

__global__ __launch_bounds__(NTHR) void lss_mega(
    const void* __restrict__ ctx, const void* __restrict__ logits,
    const void* __restrict__ s2e, const void* __restrict__ intrin,
    const void* __restrict__ ida, const void* __restrict__ bda,
    float* __restrict__ ctx_t, float* __restrict__ logits_t,
    int* __restrict__ counts, int* __restrict__ offsets,
    int* __restrict__ cursors,
    u16* __restrict__ colids, float* __restrict__ wts,
    void* __restrict__ out) {
  cg::grid_group grid = cg::this_grid();
  __shared__ union {
    float tile[16][65];                               // phase A
    struct { int cell[16][D_]; float w[16][D_]; } cf; // phases B, D (per-wave slots)
    int tmp[NTHR];                                    // phase C'
    float stage[16 * 81];                             // phase E
  } sm;
  __shared__ float s_mats[B_ * N_][32];               // [bn]: Ainv[0:16], M[16:32]
  const int tid = threadIdx.x;
  const int bid = blockIdx.x;
  const int lane = tid & 63;
  const int widx = tid >> 6;
  const int wgid = bid * (NTHR / 64) + widx;
  const int tbf = probe_tbf(logits);

  // ===== Phase 0: per-block matrix fold, once (tid 0..11) ====================
  if (tid < B_ * N_) {
    const int bn = tid, b = bn / N_;
    const int mbf = probe_mbf(intrin);
    float T[16], U[16], R[16];
    for (int i = 0; i < 16; i++) T[i] = loadf(intrin, bn * 16 + i, mbf);
    inv4(T, R);
    for (int i = 0; i < 16; i++) T[i] = loadf(s2e, bn * 16 + i, mbf);
    mul4(T, R, U);
    for (int i = 0; i < 16; i++) T[i] = loadf(bda, b * 16 + i, mbf);
    mul4(T, U, R);
    for (int i = 0; i < 16; i++) s_mats[bn][16 + i] = R[i];
    for (int i = 0; i < 16; i++) T[i] = loadf(ida, bn * 16 + i, mbf);
    inv4(T, U);
    for (int i = 0; i < 16; i++) s_mats[bn][i] = U[i];
  }
  __syncthreads();

  // ===== Phase A: LDS-tiled transposes ======================================
  const int CT = B_ * N_ * (C_ / 16) * (HW_ / 64);   // 660
  const int LT = B_ * N_ * (D_ / 16) * (HW_ / 64);   // 924
  {
    const int ty = tid >> 6, tx = tid & 63;
    const int tx2 = tid & 15, ty2 = tid >> 4;
    for (int t = bid; t < CT + LT; t += NBLK) {
      if (t < CT) {
        int bn = t / 55, rem = t % 55;
        int c0 = (rem / 11) * 16, hw0 = (rem % 11) * 64;
        sm.tile[ty][tx] = loadf(ctx, (bn * C_ + c0 + ty) * HW_ + hw0 + tx, tbf);
        __syncthreads();
        ctx_t[(bn * HW_ + hw0 + ty2) * C_ + c0 + tx2] = sm.tile[tx2][ty2];
      } else {
        int t2 = t - CT;
        int bn = t2 / 77, rem = t2 % 77;
        int d0 = (rem / 11) * 16, hw0 = (rem % 11) * 64;
        sm.tile[ty][tx] = loadf(logits, (bn * D_ + d0 + ty) * HW_ + hw0 + tx, tbf);
        __syncthreads();
        logits_t[(bn * HW_ + hw0 + ty2) * D_ + d0 + tx2] = sm.tile[tx2][ty2];
      }
      __syncthreads();
    }
  }
  __syncthreads();

  // ===== Phase B: count (per-wave LDS slot; NO block syncs inside) ==========
  for (int i = 0; i < 3; i++) {
    int col = wgid + i * NWAVES;
    if (col < NCOL) {
      int w = col % FW_, h = (col / FW_) % FH_, bn = col / HW_;
      const float* Ai = s_mats[bn];
      const float* M = s_mats[bn] + 16;
      sm.cf.cell[widx][lane] = geom_cell(Ai, M, bn, h, w, lane);
      if (lane < D_ - 64)
        sm.cf.cell[widx][lane + 64] = geom_cell(Ai, M, bn, h, w, lane + 64);
      for (int d = lane; d < D_; d += 64) {
        int vc = sm.cf.cell[widx][d];
        if (vc >= 0 && (d == 0 || sm.cf.cell[widx][d - 1] != vc))
          atomicAdd(&counts[vc], 1);
      }
    }
  }
  grid.sync();

  // ===== Phase C': redundant-base scan (no extra grid sync) =================
  {
    int lim = bid * 128;
    int partial = 0;
    for (int i = tid; i < lim; i += NTHR) partial += counts[i];
    sm.tmp[tid] = partial;
    __syncthreads();
    for (int st = 512; st > 0; st >>= 1) {
      if (tid < st) sm.tmp[tid] += sm.tmp[tid + st];
      __syncthreads();
    }
    int base = sm.tmp[0];
    __syncthreads();
    int myVal = 0;
    if (tid < 128) { myVal = counts[lim + tid]; sm.tmp[tid] = myVal; }
    __syncthreads();
    for (int st = 1; st < 128; st <<= 1) {
      int v = (tid < 128 && tid >= st) ? sm.tmp[tid - st] : 0;
      __syncthreads();
      if (tid < 128) sm.tmp[tid] += v;
      __syncthreads();
    }
    if (tid < 128) {
      int v = base + sm.tmp[tid] - myVal;
      offsets[lim + tid] = v;
      cursors[lim + tid] = v;
    }
  }
  grid.sync();

  // ===== Phase D: softmax + tuple append (no block syncs inside) ============
  for (int i = 0; i < 3; i++) {
    int col = wgid + i * NWAVES;
    if (col < NCOL) {
      int w = col % FW_, h = (col / FW_) % FH_, bn = col / HW_;
      const float* Ai = s_mats[bn];
      const float* M = s_mats[bn] + 16;
      float l0 = logits_t[col * D_ + lane];
      float l1 = (lane < D_ - 64) ? logits_t[col * D_ + 64 + lane] : -1e30f;
      float m = fmaxf(l0, l1);
      for (int s = 32; s > 0; s >>= 1) m = fmaxf(m, __shfl_xor(m, s));
      float e0 = expf(l0 - m);
      float e1 = (lane < D_ - 64) ? expf(l1 - m) : 0.f;
      float sum = e0 + e1;
      for (int s = 32; s > 0; s >>= 1) sum += __shfl_xor(sum, s);
      float inv_sum = 1.0f / sum;
      sm.cf.cell[widx][lane] = geom_cell(Ai, M, bn, h, w, lane);
      sm.cf.w[widx][lane] = e0;
      if (lane < D_ - 64) {
        sm.cf.cell[widx][lane + 64] = geom_cell(Ai, M, bn, h, w, lane + 64);
        sm.cf.w[widx][lane + 64] = e1;
      }
      for (int d = lane; d < D_; d += 64) {
        int vc = sm.cf.cell[widx][d];
        if (vc >= 0 && (d == 0 || sm.cf.cell[widx][d - 1] != vc)) {
          float acc = sm.cf.w[widx][d];
          for (int j = d + 1; j < D_ && sm.cf.cell[widx][j] == vc; ++j)
            acc += sm.cf.w[widx][j];
          int pos = atomicAdd(&cursors[vc], 1);
          colids[pos] = (u16)col;
          wts[pos] = acc * inv_sum;
        }
      }
    }
  }
  grid.sync();

  // ===== Phase E: gather, ONE WAVE PER CELL (8 slices x 8 ch-groups of 10) ==
  for (int p = 0; p < NCELL / (NBLK * 16); p++) {     // 8 passes
    int cell0 = (p * NBLK + bid) * 16;
    int cell = cell0 + widx;
    int n = counts[cell];
    int off = offsets[cell];
    int sl = lane >> 3;           // j-slice 0..7
    int g = lane & 7;             // channel group: 10 channels
    float acc[10];
#pragma unroll
    for (int i = 0; i < 10; i++) acc[i] = 0.f;
    for (int j = sl; j < n; j += 8) {
      int colj = colids[off + j];
      float wj = wts[off + j];
      const float2* cp = (const float2*)(ctx_t + colj * C_ + g * 10);
#pragma unroll
      for (int q = 0; q < 5; q++) {
        float2 v = cp[q];
        acc[q * 2 + 0] += wj * v.x;
        acc[q * 2 + 1] += wj * v.y;
      }
    }
#pragma unroll
    for (int msk = 8; msk <= 32; msk <<= 1) {
#pragma unroll
      for (int i = 0; i < 10; i++) acc[i] += __shfl_xor(acc[i], msk);
    }
    if (sl == 0) {
#pragma unroll
      for (int i = 0; i < 10; i++) sm.stage[widx * 81 + g * 10 + i] = acc[i];
    }
    __syncthreads();
    {
      int b = cell0 >> 14;
      int yx0 = cell0 & 16383;
      int x = tid & 15;
      int c = tid >> 4;           // 0..63
      float v0 = sm.stage[x * 81 + c];
      size_t oi = ((size_t)(b * C_ + c) << 14) + yx0 + x;
      if (tbf) ((bf16*)out)[oi] = __float2bfloat16(v0);
      else ((float*)out)[oi] = v0;
      if (c < 16) {
        float v1 = sm.stage[x * 81 + 64 + c];
        size_t oi2 = ((size_t)(b * C_ + 64 + c) << 14) + yx0 + x;
        if (tbf) ((bf16*)out)[oi2] = __float2bfloat16(v1);
        else ((float*)out)[oi2] = v1;
      }
    }
    __syncthreads();
  }
}

extern "C" void kernel_launch(void* const* d_in, const int* in_sizes, int n_in,
                              void* d_out, int out_size, void* d_ws, size_t ws_size,
                              hipStream_t stream) {
  const void* ctx = d_in[0];
  const void* logits = d_in[1];
  const void* s2e = d_in[2];
  const void* intrin = d_in[3];
  const void* ida = d_in[4];
  const void* bda = d_in[5];

  int* counts     = (int*)d_ws;
  int* offsets    = counts + NCELL;
  int* cursors    = offsets + NCELL;
  float* ctx_t    = (float*)(cursors + NCELL);
  float* logits_t = ctx_t + NCOL * C_;
  u16* colids     = (u16*)(logits_t + NCOL * D_);
  float* wts      = (float*)(colids + MAXT);
  void* outp      = d_out;

  hipMemsetAsync(counts, 0, NCELL * sizeof(int), stream);
  void* args[] = {(void*)&ctx, (void*)&logits, (void*)&s2e, (void*)&intrin,
                  (void*)&ida, (void*)&bda, (void*)&ctx_t, (void*)&logits_t,
                  (void*)&counts, (void*)&offsets, (void*)&cursors,
                  (void*)&colids, (void*)&wts, (void*)&outp};
  hipLaunchCooperativeKernel((void*)lss_mega, dim3(NBLK), dim3(NTHR), args, 0, stream);
}